// Round 4
// baseline (135.565 us; speedup 1.0000x reference)
//
#include <hip/hip_runtime.h>
#include <hip/hip_bf16.h>

#define C_ 256
#define H_ 8
#define DH_ 32
#define L_ 1024

typedef __bf16 bf16x8_t __attribute__((ext_vector_type(8)));
typedef float f32x4_t __attribute__((ext_vector_type(4)));

union V16 {
    uint4 u4;
    bf16x8_t b8;
    f32x4_t f4;
    unsigned u[4];
};

__device__ __forceinline__ unsigned cvt_pk(float lo, float hi) {
    unsigned r;
    asm volatile("v_cvt_pk_bf16_f32 %0, %1, %2" : "=v"(r) : "v"(lo), "v"(hi));
    return r;
}

__device__ __forceinline__ f32x4_t mfma16(bf16x8_t a, bf16x8_t b, f32x4_t c) {
    return __builtin_amdgcn_mfma_f32_16x16x32_bf16(a, b, c, 0, 0, 0);
}

__device__ __forceinline__ unsigned short f2bf(float f) {
    unsigned u = __float_as_uint(f);
    u += 0x7fffu + ((u >> 16) & 1u);
    return (unsigned short)(u >> 16);
}

__device__ __forceinline__ float bfup(unsigned short u) {
    return __uint_as_float((unsigned)u << 16);
}

// ---------------- K0: convert x, bulk, weights -> bf16 ----------------
// grid (2048, 6), block 256. y: 0=x, 1=bulk, 2..5=Wq/Wk/Wv/Wo.
__global__ __launch_bounds__(256) void conv_bf16(
    const float* __restrict__ x, const float* __restrict__ bulk,
    const float* __restrict__ Wq, const float* __restrict__ Wk,
    const float* __restrict__ Wv, const float* __restrict__ Wo,
    unsigned short* __restrict__ xb, unsigned short* __restrict__ bulkb,
    unsigned short* __restrict__ wb)
{
    int ysel = blockIdx.y;
    const float* src; unsigned short* dst; int n4;
    if (ysel == 0)      { src = x;    dst = xb;    n4 = 524288; }
    else if (ysel == 1) { src = bulk; dst = bulkb; n4 = 524288; }
    else {
        src = (ysel == 2) ? Wq : (ysel == 3) ? Wk : (ysel == 4) ? Wv : Wo;
        dst = wb + (ysel - 2) * 65536; n4 = 16384;
    }
    int i = blockIdx.x * 256 + threadIdx.x;
    if (i >= n4) return;
    float4 v = ((const float4*)src)[i];
    ushort4 o;
    o.x = f2bf(v.x); o.y = f2bf(v.y); o.z = f2bf(v.z); o.w = f2bf(v.w);
    ((ushort4*)dst)[i] = o;
}

// ---------------- K1: QKV projection via MFMA ----------------
// grid (128, 12), block 256 = 4 waves (2m x 2n), wave = 32m x 32n, K=256.
__global__ __launch_bounds__(256) void qkv_mfma(
    const unsigned short* __restrict__ xb, const unsigned short* __restrict__ wb,
    const float* __restrict__ bq, const float* __restrict__ bk, const float* __restrict__ bv,
    unsigned short* __restrict__ qws, unsigned short* __restrict__ kws,
    unsigned short* __restrict__ vws)
{
    const int t = threadIdx.x;
    const int lane = t & 63, w = t >> 6;
    const int r = lane & 15, g = lane >> 4;
    const int m0 = blockIdx.x * 64 + (w >> 1) * 32;
    const int n0g = blockIdx.y * 64 + (w & 1) * 32;
    const int z = n0g >> 8, nl = n0g & 255;

    const uint4* ap = (const uint4*)xb;
    const uint4* bp = (const uint4*)(wb + z * 65536);

    f32x4_t acc[2][2] = {};
#pragma unroll
    for (int kt = 0; kt < 8; ++kt) {
        V16 a0, a1, b0, b1;
        a0.u4 = ap[(m0 + r) * 32 + kt * 4 + g];
        a1.u4 = ap[(m0 + 16 + r) * 32 + kt * 4 + g];
        b0.u4 = bp[(nl + r) * 32 + kt * 4 + g];
        b1.u4 = bp[(nl + 16 + r) * 32 + kt * 4 + g];
        acc[0][0] = mfma16(a0.b8, b0.b8, acc[0][0]);
        acc[0][1] = mfma16(a0.b8, b1.b8, acc[0][1]);
        acc[1][0] = mfma16(a1.b8, b0.b8, acc[1][0]);
        acc[1][1] = mfma16(a1.b8, b1.b8, acc[1][1]);
    }

    const float* bias = (z == 0) ? bq : (z == 1) ? bk : bv;
    unsigned short* dst = (z == 0) ? qws : (z == 1) ? kws : vws;
    const float sc = (z == 0) ? 0.17677669529663687f : 1.0f;
    float bv0 = bias[nl + r], bv1 = bias[nl + 16 + r];
#pragma unroll
    for (int mi = 0; mi < 2; ++mi)
#pragma unroll
        for (int ni = 0; ni < 2; ++ni) {
            int n = nl + ni * 16 + r;
            int h = n >> 5, d = n & 31;
            float bb = ni ? bv1 : bv0;
#pragma unroll
            for (int e = 0; e < 4; ++e) {
                int m = m0 + mi * 16 + g * 4 + e;
                int bs = m >> 10, l = m & 1023;
                float val = (acc[mi][ni][e] + bb) * sc;
                dst[((size_t)((bs * H_ + h) * L_ + l)) * DH_ + d] = f2bf(val);
            }
        }
}

// ---------------- K1b: transpose V per head: [hb][l][d] -> [hb][d][l] ----------------
__global__ __launch_bounds__(256) void transpose_v(const unsigned short* __restrict__ vws,
                                                   unsigned short* __restrict__ vT)
{
    __shared__ unsigned short tile[32][264];
    int hb = blockIdx.y;
    int l0 = blockIdx.x * 256;
    int t = threadIdx.x;
    const unsigned* src = (const unsigned*)(vws + (size_t)hb * 32768) + l0 * 16;
    for (int i = t; i < 4096; i += 256) {
        int l = i >> 4, d2 = i & 15;
        unsigned u = src[i];
        tile[d2 * 2][l]     = (unsigned short)(u & 0xffffu);
        tile[d2 * 2 + 1][l] = (unsigned short)(u >> 16);
    }
    __syncthreads();
    unsigned* dst = (unsigned*)(vT + (size_t)hb * 32768);
    int d = t >> 3, seg = (t & 7) * 32;
#pragma unroll
    for (int j = 0; j < 16; ++j) {
        int l = seg + j * 2;
        unsigned u = (unsigned)tile[d][l] | ((unsigned)tile[d][l + 1] << 16);
        dst[d * 512 + (l0 + l) / 2] = u;
    }
}

// ---------------- K2: MFMA flash attention + fused gate ----------------
// grid (32, 16), block 512 = 8 waves = 4 tracks x 2 q-halves; wave = 16 q rows.
#define LOADK(DST, KV)                                                         \
    {                                                                          \
        _Pragma("unroll") for (int m_ = 0; m_ < 4; ++m_) {                     \
            V16 tmp_; tmp_.u4 = kp[((KV) + m_ * 16 + r) * 4 + g];              \
            DST[m_] = tmp_.b8;                                                 \
        }                                                                      \
    }
#define LOADB(DST, KV)                                                         \
    {                                                                          \
        _Pragma("unroll") for (int m_ = 0; m_ < 4; ++m_)                       \
            DST[m_] = bp4[(q0 + r) * 256 + (((KV) + m_ * 16) >> 2) + g];       \
    }

__global__ __launch_bounds__(512, 4) void attn_mfma(
    const unsigned short* __restrict__ qws, const unsigned short* __restrict__ kws,
    const unsigned short* __restrict__ vT, const unsigned short* __restrict__ bulkb,
    const float* __restrict__ conv_w, const float* __restrict__ conv_b,
    const float* __restrict__ gate_w, const float* __restrict__ gate_b,
    unsigned short* __restrict__ ogb)
{
    const int t = threadIdx.x;
    const int lane = t & 63, w = t >> 6;
    const int g = lane >> 4, r = lane & 15;
    const int s = w & 3, qh = w >> 2;
    const int h = blockIdx.y & 7, b = blockIdx.y >> 3;
    const int hb = (b * 4 + s) * 8 + h;
    const int q0 = blockIdx.x * 32 + qh * 16;

    const uint4* kp = (const uint4*)(kws + (size_t)hb * 32768);
    const uint4* qp = (const uint4*)(qws + (size_t)hb * 32768);
    const uint4* vp = (const uint4*)(vT  + (size_t)hb * 32768);
    const ushort4* bp4 = (const ushort4*)(bulkb + (size_t)b * 1048576);
    const float cw = conv_w[h], cb = conv_b[h];

    // Q B-frag: lane holds Q[q0+r][g*8 .. g*8+7]
    bf16x8_t qb;
    { V16 tmp; tmp.u4 = qp[(q0 + r) * 4 + g]; qb = tmp.b8; }

    f32x4_t o[2] = {};              // O^T: row d = md*16+g*4+e, col q = r
    float mst = -3.0e38f, lst = 0.f;

    bf16x8_t KA[4], KB[4];
    ushort4 BA[4], BB[4];
    LOADK(KA, 0)
    LOADB(BA, 0)

#define PHASE(KC, BC, KV0, KN, BN, KVN)                                        \
    {                                                                          \
        const int kv0_ = (KV0);                                                \
        uint4 vau[4];                                                          \
        _Pragma("unroll") for (int md_ = 0; md_ < 2; ++md_)                    \
        _Pragma("unroll") for (int s2_ = 0; s2_ < 2; ++s2_)                    \
            vau[md_ * 2 + s2_] = vp[(md_ * 16 + r) * 128 + (kv0_ >> 3) + s2_ * 4 + g]; \
        LOADK(KN, (KVN))                                                       \
        LOADB(BN, (KVN))                                                       \
        f32x4_t acc[4];                                                        \
        _Pragma("unroll") for (int m_ = 0; m_ < 4; ++m_) {                     \
            f32x4_t b4_;                                                       \
            b4_[0] = bfup(BC[m_].x); b4_[1] = bfup(BC[m_].y);                  \
            b4_[2] = bfup(BC[m_].z); b4_[3] = bfup(BC[m_].w);                  \
            acc[m_] = cw * b4_ + cb;                                           \
        }                                                                      \
        __builtin_amdgcn_s_setprio(1);                                         \
        _Pragma("unroll") for (int m_ = 0; m_ < 4; ++m_)                       \
            acc[m_] = mfma16(KC[m_], qb, acc[m_]);                             \
        __builtin_amdgcn_s_setprio(0);                                         \
        float pmax = acc[0][0];                                                \
        _Pragma("unroll") for (int m_ = 0; m_ < 4; ++m_)                       \
        _Pragma("unroll") for (int e_ = 0; e_ < 4; ++e_)                       \
            pmax = fmaxf(pmax, acc[m_][e_]);                                   \
        pmax = fmaxf(pmax, __shfl_xor(pmax, 16, 64));                          \
        pmax = fmaxf(pmax, __shfl_xor(pmax, 32, 64));                          \
        if (!__all(pmax <= mst + 8.0f)) {                                      \
            float mnew = fmaxf(mst, pmax);                                     \
            float scale = __expf(mst - mnew);                                  \
            mst = mnew; lst *= scale;                                          \
            o[0] *= scale; o[1] *= scale;                                      \
        }                                                                      \
        float psum = 0.f;                                                      \
        _Pragma("unroll") for (int m_ = 0; m_ < 4; ++m_)                       \
        _Pragma("unroll") for (int e_ = 0; e_ < 4; ++e_) {                     \
            float p_ = __expf(acc[m_][e_] - mst);                              \
            acc[m_][e_] = p_; psum += p_;                                      \
        }                                                                      \
        psum += __shfl_xor(psum, 16, 64);                                      \
        psum += __shfl_xor(psum, 32, 64);                                      \
        lst += psum;                                                           \
        unsigned pk[4][2];                                                     \
        _Pragma("unroll") for (int m_ = 0; m_ < 4; ++m_) {                     \
            pk[m_][0] = cvt_pk(acc[m_][0], acc[m_][1]);                        \
            pk[m_][1] = cvt_pk(acc[m_][2], acc[m_][3]);                        \
        }                                                                      \
        _Pragma("unroll") for (int s2_ = 0; s2_ < 2; ++s2_) {                  \
            V16 pb;                                                            \
            _Pragma("unroll") for (int u_ = 0; u_ < 4; ++u_) {                 \
                int srcl_ = ((2 * (g & 1) + (u_ >> 1)) << 4) | r;              \
                unsigned lo_ = (unsigned)__shfl((int)pk[2 * s2_][u_ & 1], srcl_, 64);     \
                unsigned hi_ = (unsigned)__shfl((int)pk[2 * s2_ + 1][u_ & 1], srcl_, 64); \
                pb.u[u_] = (g >= 2) ? hi_ : lo_;                               \
            }                                                                  \
            V16 va0_; va0_.u4 = vau[0 * 2 + s2_];                              \
            V16 va1_; va1_.u4 = vau[1 * 2 + s2_];                              \
            __builtin_amdgcn_s_setprio(1);                                     \
            o[0] = mfma16(va0_.b8, pb.b8, o[0]);                               \
            o[1] = mfma16(va1_.b8, pb.b8, o[1]);                               \
            __builtin_amdgcn_s_setprio(0);                                     \
        }                                                                      \
    }

    for (int kt = 0; kt < 16; kt += 2) {
        PHASE(KA, BA, kt * 64, KB, BB, (kt + 1) * 64)
        int kv2 = (kt + 2 < 16) ? (kt + 2) * 64 : 0;
        PHASE(KB, BB, (kt + 1) * 64, KA, BA, kv2)
    }

    // ---- epilogue: normalize, fused gate, store og as bf16 ----
    float linv = 1.0f / lst;
    o[0] *= linv;
    o[1] *= linv;

    // gate_w A-frags + gate_b (loaded here to keep main-loop VGPR low)
    bf16x8_t ga[2]; f32x4_t gb4[2];
#pragma unroll
    for (int mc = 0; mc < 2; ++mc) {
        const float* gwp = gate_w + (size_t)(h * 32 + mc * 16 + r) * 32 + g * 8;
        f32x4_t w0 = *(const f32x4_t*)gwp;
        f32x4_t w1 = *(const f32x4_t*)(gwp + 4);
        V16 tmp;
        tmp.u[0] = cvt_pk(w0[0], w0[1]); tmp.u[1] = cvt_pk(w0[2], w0[3]);
        tmp.u[2] = cvt_pk(w1[0], w1[1]); tmp.u[3] = cvt_pk(w1[2], w1[3]);
        ga[mc] = tmp.b8;
        gb4[mc] = *(const f32x4_t*)(gate_b + h * 32 + mc * 16 + g * 4);
    }

    unsigned pkO[2][2];
#pragma unroll
    for (int md = 0; md < 2; ++md) {
        pkO[md][0] = cvt_pk(o[md][0], o[md][1]);
        pkO[md][1] = cvt_pk(o[md][2], o[md][3]);
    }
    V16 ob;
#pragma unroll
    for (int u = 0; u < 4; ++u) {
        int srcl = ((2 * (g & 1) + (u >> 1)) << 4) | r;
        unsigned lo = (unsigned)__shfl((int)pkO[0][u & 1], srcl, 64);
        unsigned hi = (unsigned)__shfl((int)pkO[1][u & 1], srcl, 64);
        ob.u[u] = (g >= 2) ? hi : lo;
    }
    f32x4_t zero = {0.f, 0.f, 0.f, 0.f};
    f32x4_t gacc0 = mfma16(ga[0], ob.b8, zero);
    f32x4_t gacc1 = mfma16(ga[1], ob.b8, zero);
#pragma unroll
    for (int e = 0; e < 4; ++e) {
        float s0 = 1.0f / (1.0f + __expf(-(gacc0[e] + gb4[0][e])));
        float s1 = 1.0f / (1.0f + __expf(-(gacc1[e] + gb4[1][e])));
        o[0][e] *= s0;
        o[1][e] *= s1;
    }
    unsigned* ogp = (unsigned*)ogb;
#pragma unroll
    for (int md = 0; md < 2; ++md) {
        uint2 st;
        st.x = cvt_pk(o[md][0], o[md][1]);
        st.y = cvt_pk(o[md][2], o[md][3]);
        *(uint2*)&ogp[((size_t)(hb * 1024 + q0 + r)) * 16 + md * 8 + g * 2] = st;
    }
}

// ---------------- K3: out-proj + residual + layernorm via MFMA ----------------
// grid 512, block 512 = 8 waves; block = 16m x 256n, wave = 16m x 32n.
__global__ __launch_bounds__(512) void proj_ln_mfma(
    const unsigned short* __restrict__ ogb, const float* __restrict__ x,
    const unsigned short* __restrict__ wob, const float* __restrict__ bo,
    const float* __restrict__ ln_g, const float* __restrict__ ln_b,
    float* __restrict__ out)
{
    __shared__ float s1l[8][16];
    __shared__ float s2l[8][16];
    const int t = threadIdx.x;
    const int lane = t & 63, w = t >> 6;
    const int r = lane & 15, g = lane >> 4;
    const int m0 = blockIdx.x * 16;
    const int bs = m0 >> 10, l0 = m0 & 1023;
    const int n0 = w * 32;

    const uint4* ap = (const uint4*)ogb;
    const uint4* bp = (const uint4*)wob;

    f32x4_t acc[2] = {};
#pragma unroll
    for (int kt = 0; kt < 8; ++kt) {
        V16 a0, b0, b1;
        a0.u4 = ap[((size_t)(bs * 8 + kt) * 1024 + l0 + r) * 4 + g];
        b0.u4 = bp[(n0 + r) * 32 + kt * 4 + g];
        b1.u4 = bp[(n0 + 16 + r) * 32 + kt * 4 + g];
        acc[0] = mfma16(a0.b8, b0.b8, acc[0]);
        acc[1] = mfma16(a0.b8, b1.b8, acc[1]);
    }

    float bo0 = bo[n0 + r], bo1 = bo[n0 + 16 + r];
#pragma unroll
    for (int e = 0; e < 4; ++e) {
        int m = m0 + g * 4 + e;
        acc[0][e] += bo0 + x[(size_t)m * 256 + n0 + r];
        acc[1][e] += bo1 + x[(size_t)m * 256 + n0 + 16 + r];
    }
    // per-lane partial row sums over this wave's 32 cols
#pragma unroll
    for (int e = 0; e < 4; ++e) {
        float sm = acc[0][e] + acc[1][e];
        float sq = acc[0][e] * acc[0][e] + acc[1][e] * acc[1][e];
        sm += __shfl_xor(sm, 1, 64); sq += __shfl_xor(sq, 1, 64);
        sm += __shfl_xor(sm, 2, 64); sq += __shfl_xor(sq, 2, 64);
        sm += __shfl_xor(sm, 4, 64); sq += __shfl_xor(sq, 4, 64);
        sm += __shfl_xor(sm, 8, 64); sq += __shfl_xor(sq, 8, 64);
        if (r == 0) { s1l[w][g * 4 + e] = sm; s2l[w][g * 4 + e] = sq; }
    }
    __syncthreads();

    float g0 = ln_g[n0 + r], g1 = ln_g[n0 + 16 + r];
    float b0 = ln_b[n0 + r], b1 = ln_b[n0 + 16 + r];
#pragma unroll
    for (int e = 0; e < 4; ++e) {
        int mloc = g * 4 + e;
        float sm = 0.f, sq = 0.f;
#pragma unroll
        for (int wv = 0; wv < 8; ++wv) { sm += s1l[wv][mloc]; sq += s2l[wv][mloc]; }
        float mu = sm * (1.0f / 256.0f);
        float var = sq * (1.0f / 256.0f) - mu * mu;
        float rs = rsqrtf(var + 1e-5f);
        int m = m0 + mloc;
        out[(size_t)m * 256 + n0 + r]      = (acc[0][e] - mu) * rs * g0 + b0;
        out[(size_t)m * 256 + n0 + 16 + r] = (acc[1][e] - mu) * rs * g1 + b1;
    }
}

extern "C" void kernel_launch(void* const* d_in, const int* in_sizes, int n_in,
                              void* d_out, int out_size, void* d_ws, size_t ws_size,
                              hipStream_t stream)
{
    (void)in_sizes; (void)n_in; (void)out_size; (void)ws_size;
    const float* x      = (const float*)d_in[0];
    const float* bulk   = (const float*)d_in[1];
    const float* Wq     = (const float*)d_in[2];
    const float* bq     = (const float*)d_in[3];
    const float* Wk     = (const float*)d_in[4];
    const float* bk     = (const float*)d_in[5];
    const float* Wv     = (const float*)d_in[6];
    const float* bv     = (const float*)d_in[7];
    const float* Wo     = (const float*)d_in[8];
    const float* bo     = (const float*)d_in[9];
    const float* conv_w = (const float*)d_in[10];
    const float* conv_b = (const float*)d_in[11];
    const float* gate_w = (const float*)d_in[12];
    const float* gate_b = (const float*)d_in[13];
    const float* ln_g   = (const float*)d_in[14];
    const float* ln_b   = (const float*)d_in[15];
    float* out = (float*)d_out;

    char* ws = (char*)d_ws;
    unsigned short* xb    = (unsigned short*)ws;                  // 4 MB
    unsigned short* bulkb = (unsigned short*)(ws + (4u << 20));   // 4 MB
    unsigned short* wb    = (unsigned short*)(ws + (8u << 20));   // 512 KB (4 x 256x256)
    unsigned short* qws   = (unsigned short*)(ws + (8u << 20) + (512u << 10)); // 4 MB
    unsigned short* kws   = qws + 2097152;                        // 4 MB
    unsigned short* vws   = qws + 4194304;                        // 4 MB
    unsigned short* vT    = qws + 6291456;                        // 4 MB
    unsigned short* ogb   = vws;  // alias: vws dead after transpose_v (stream-ordered)
    unsigned short* wob   = wb + 3 * 65536;

    conv_bf16<<<dim3(2048, 6), 256, 0, stream>>>(x, bulk, Wq, Wk, Wv, Wo, xb, bulkb, wb);
    qkv_mfma<<<dim3(128, 12), 256, 0, stream>>>(xb, wb, bq, bk, bv, qws, kws, vws);
    transpose_v<<<dim3(4, 64), 256, 0, stream>>>(vws, vT);
    attn_mfma<<<dim3(32, 16), 512, 0, stream>>>(qws, kws, vT, bulkb, conv_w, conv_b,
                                                gate_w, gate_b, ogb);
    proj_ln_mfma<<<512, 512, 0, stream>>>(ogb, x, wob, bo, ln_g, ln_b, out);
}

// Round 5
// 135.446 us; speedup vs baseline: 1.0009x; 1.0009x over previous
//
#include <hip/hip_runtime.h>
#include <hip/hip_bf16.h>

#define C_ 256
#define H_ 8
#define DH_ 32
#define L_ 1024

typedef __bf16 bf16x8_t __attribute__((ext_vector_type(8)));
typedef float f32x4_t __attribute__((ext_vector_type(4)));

union V16 {
    uint4 u4;
    bf16x8_t b8;
    f32x4_t f4;
    unsigned u[4];
};

__device__ __forceinline__ unsigned cvt_pk(float lo, float hi) {
    unsigned r;
    asm volatile("v_cvt_pk_bf16_f32 %0, %1, %2" : "=v"(r) : "v"(lo), "v"(hi));
    return r;
}

__device__ __forceinline__ f32x4_t mfma16(bf16x8_t a, bf16x8_t b, f32x4_t c) {
    return __builtin_amdgcn_mfma_f32_16x16x32_bf16(a, b, c, 0, 0, 0);
}

__device__ __forceinline__ unsigned short f2bf(float f) {
    unsigned u = __float_as_uint(f);
    u += 0x7fffu + ((u >> 16) & 1u);
    return (unsigned short)(u >> 16);
}

__device__ __forceinline__ float bfup(unsigned short u) {
    return __uint_as_float((unsigned)u << 16);
}

// ---------------- K0: convert x, bulk, weights -> bf16 ----------------
// grid (2048, 6), block 256. y: 0=x, 1=bulk, 2..5=Wq/Wk/Wv/Wo.
__global__ __launch_bounds__(256) void conv_bf16(
    const float* __restrict__ x, const float* __restrict__ bulk,
    const float* __restrict__ Wq, const float* __restrict__ Wk,
    const float* __restrict__ Wv, const float* __restrict__ Wo,
    unsigned short* __restrict__ xb, unsigned short* __restrict__ bulkb,
    unsigned short* __restrict__ wb)
{
    int ysel = blockIdx.y;
    const float* src; unsigned short* dst; int n4;
    if (ysel == 0)      { src = x;    dst = xb;    n4 = 524288; }
    else if (ysel == 1) { src = bulk; dst = bulkb; n4 = 524288; }
    else {
        src = (ysel == 2) ? Wq : (ysel == 3) ? Wk : (ysel == 4) ? Wv : Wo;
        dst = wb + (ysel - 2) * 65536; n4 = 16384;
    }
    int i = blockIdx.x * 256 + threadIdx.x;
    if (i >= n4) return;
    float4 v = ((const float4*)src)[i];
    ushort4 o;
    o.x = f2bf(v.x); o.y = f2bf(v.y); o.z = f2bf(v.z); o.w = f2bf(v.w);
    ((ushort4*)dst)[i] = o;
}

// ---------------- K1: QKV projection via MFMA ----------------
// grid (128, 12), block 256 = 4 waves (2m x 2n), wave = 32m x 32n, K=256.
__global__ __launch_bounds__(256) void qkv_mfma(
    const unsigned short* __restrict__ xb, const unsigned short* __restrict__ wb,
    const float* __restrict__ bq, const float* __restrict__ bk, const float* __restrict__ bv,
    unsigned short* __restrict__ qws, unsigned short* __restrict__ kws,
    unsigned short* __restrict__ vws)
{
    const int t = threadIdx.x;
    const int lane = t & 63, w = t >> 6;
    const int r = lane & 15, g = lane >> 4;
    const int m0 = blockIdx.x * 64 + (w >> 1) * 32;
    const int n0g = blockIdx.y * 64 + (w & 1) * 32;
    const int z = n0g >> 8, nl = n0g & 255;

    const uint4* ap = (const uint4*)xb;
    const uint4* bp = (const uint4*)(wb + z * 65536);

    f32x4_t acc[2][2] = {};
#pragma unroll
    for (int kt = 0; kt < 8; ++kt) {
        V16 a0, a1, b0, b1;
        a0.u4 = ap[(m0 + r) * 32 + kt * 4 + g];
        a1.u4 = ap[(m0 + 16 + r) * 32 + kt * 4 + g];
        b0.u4 = bp[(nl + r) * 32 + kt * 4 + g];
        b1.u4 = bp[(nl + 16 + r) * 32 + kt * 4 + g];
        acc[0][0] = mfma16(a0.b8, b0.b8, acc[0][0]);
        acc[0][1] = mfma16(a0.b8, b1.b8, acc[0][1]);
        acc[1][0] = mfma16(a1.b8, b0.b8, acc[1][0]);
        acc[1][1] = mfma16(a1.b8, b1.b8, acc[1][1]);
    }

    const float* bias = (z == 0) ? bq : (z == 1) ? bk : bv;
    unsigned short* dst = (z == 0) ? qws : (z == 1) ? kws : vws;
    const float sc = (z == 0) ? 0.17677669529663687f : 1.0f;
    float bv0 = bias[nl + r], bv1 = bias[nl + 16 + r];
#pragma unroll
    for (int mi = 0; mi < 2; ++mi)
#pragma unroll
        for (int ni = 0; ni < 2; ++ni) {
            int n = nl + ni * 16 + r;
            int h = n >> 5, d = n & 31;
            float bb = ni ? bv1 : bv0;
#pragma unroll
            for (int e = 0; e < 4; ++e) {
                int m = m0 + mi * 16 + g * 4 + e;
                int bs = m >> 10, l = m & 1023;
                float val = (acc[mi][ni][e] + bb) * sc;
                dst[((size_t)((bs * H_ + h) * L_ + l)) * DH_ + d] = f2bf(val);
            }
        }
}

// ---------------- K1b: transpose V per head: [hb][l][d] -> [hb][d][l] ----------------
__global__ __launch_bounds__(256) void transpose_v(const unsigned short* __restrict__ vws,
                                                   unsigned short* __restrict__ vT)
{
    __shared__ unsigned short tile[32][264];
    int hb = blockIdx.y;
    int l0 = blockIdx.x * 256;
    int t = threadIdx.x;
    const unsigned* src = (const unsigned*)(vws + (size_t)hb * 32768) + l0 * 16;
    for (int i = t; i < 4096; i += 256) {
        int l = i >> 4, d2 = i & 15;
        unsigned u = src[i];
        tile[d2 * 2][l]     = (unsigned short)(u & 0xffffu);
        tile[d2 * 2 + 1][l] = (unsigned short)(u >> 16);
    }
    __syncthreads();
    unsigned* dst = (unsigned*)(vT + (size_t)hb * 32768);
    int d = t >> 3, seg = (t & 7) * 32;
#pragma unroll
    for (int j = 0; j < 16; ++j) {
        int l = seg + j * 2;
        unsigned u = (unsigned)tile[d][l] | ((unsigned)tile[d][l + 1] << 16);
        dst[d * 512 + (l0 + l) / 2] = u;
    }
}

// ---------------- K2: MFMA flash attention + fused gate ----------------
// grid (32, 16), block 512 = 8 waves = 4 tracks x 2 q-halves; wave = 16 q rows.
#define LOADK(DST, KV)                                                         \
    {                                                                          \
        _Pragma("unroll") for (int m_ = 0; m_ < 4; ++m_) {                     \
            V16 tmp_; tmp_.u4 = kp[((KV) + m_ * 16 + r) * 4 + g];              \
            DST[m_] = tmp_.b8;                                                 \
        }                                                                      \
    }
#define LOADB(DST, KV)                                                         \
    {                                                                          \
        _Pragma("unroll") for (int m_ = 0; m_ < 4; ++m_)                       \
            DST[m_] = bp4[(q0 + r) * 256 + (((KV) + m_ * 16) >> 2) + g];       \
    }

__global__ __launch_bounds__(512, 4) void attn_mfma(
    const unsigned short* __restrict__ qws, const unsigned short* __restrict__ kws,
    const unsigned short* __restrict__ vT, const unsigned short* __restrict__ bulkb,
    const float* __restrict__ conv_w, const float* __restrict__ conv_b,
    const float* __restrict__ gate_w, const float* __restrict__ gate_b,
    unsigned short* __restrict__ ogb)
{
    const int t = threadIdx.x;
    const int lane = t & 63, w = t >> 6;
    const int g = lane >> 4, r = lane & 15;
    const int s = w & 3, qh = w >> 2;
    const int h = blockIdx.y & 7, b = blockIdx.y >> 3;
    const int hb = (b * 4 + s) * 8 + h;
    const int q0 = blockIdx.x * 32 + qh * 16;

    const uint4* kp = (const uint4*)(kws + (size_t)hb * 32768);
    const uint4* qp = (const uint4*)(qws + (size_t)hb * 32768);
    const uint4* vp = (const uint4*)(vT  + (size_t)hb * 32768);
    const ushort4* bp4 = (const ushort4*)(bulkb + (size_t)b * 1048576);
    const float cw = conv_w[h], cb = conv_b[h];

    // Q B-frag: lane holds Q[q0+r][g*8 .. g*8+7]
    bf16x8_t qb;
    { V16 tmp; tmp.u4 = qp[(q0 + r) * 4 + g]; qb = tmp.b8; }

    f32x4_t o[2] = {};              // O^T: row d = md*16+g*4+e, col q = r
    float mst = -3.0e38f, lst = 0.f;

    bf16x8_t KA[4], KB[4];
    ushort4 BA[4], BB[4];
    LOADK(KA, 0)
    LOADB(BA, 0)

#define PHASE(KC, BC, KV0, KN, BN, KVN)                                        \
    {                                                                          \
        const int kv0_ = (KV0);                                                \
        uint4 vau[4];                                                          \
        _Pragma("unroll") for (int md_ = 0; md_ < 2; ++md_)                    \
        _Pragma("unroll") for (int s2_ = 0; s2_ < 2; ++s2_)                    \
            vau[md_ * 2 + s2_] = vp[(md_ * 16 + r) * 128 + (kv0_ >> 3) + s2_ * 4 + g]; \
        LOADK(KN, (KVN))                                                       \
        LOADB(BN, (KVN))                                                       \
        f32x4_t acc[4];                                                        \
        _Pragma("unroll") for (int m_ = 0; m_ < 4; ++m_) {                     \
            f32x4_t b4_;                                                       \
            b4_[0] = bfup(BC[m_].x); b4_[1] = bfup(BC[m_].y);                  \
            b4_[2] = bfup(BC[m_].z); b4_[3] = bfup(BC[m_].w);                  \
            acc[m_] = cw * b4_ + cb;                                           \
        }                                                                      \
        __builtin_amdgcn_s_setprio(1);                                         \
        _Pragma("unroll") for (int m_ = 0; m_ < 4; ++m_)                       \
            acc[m_] = mfma16(KC[m_], qb, acc[m_]);                             \
        __builtin_amdgcn_s_setprio(0);                                         \
        float pmax = acc[0][0];                                                \
        _Pragma("unroll") for (int m_ = 0; m_ < 4; ++m_)                       \
        _Pragma("unroll") for (int e_ = 0; e_ < 4; ++e_)                       \
            pmax = fmaxf(pmax, acc[m_][e_]);                                   \
        pmax = fmaxf(pmax, __shfl_xor(pmax, 16, 64));                          \
        pmax = fmaxf(pmax, __shfl_xor(pmax, 32, 64));                          \
        if (!__all(pmax <= mst + 8.0f)) {                                      \
            float mnew = fmaxf(mst, pmax);                                     \
            float scale = __expf(mst - mnew);                                  \
            mst = mnew; lst *= scale;                                          \
            o[0] *= scale; o[1] *= scale;                                      \
        }                                                                      \
        float psum = 0.f;                                                      \
        _Pragma("unroll") for (int m_ = 0; m_ < 4; ++m_)                       \
        _Pragma("unroll") for (int e_ = 0; e_ < 4; ++e_) {                     \
            float p_ = __expf(acc[m_][e_] - mst);                              \
            acc[m_][e_] = p_; psum += p_;                                      \
        }                                                                      \
        psum += __shfl_xor(psum, 16, 64);                                      \
        psum += __shfl_xor(psum, 32, 64);                                      \
        lst += psum;                                                           \
        unsigned pk[4][2];                                                     \
        _Pragma("unroll") for (int m_ = 0; m_ < 4; ++m_) {                     \
            pk[m_][0] = cvt_pk(acc[m_][0], acc[m_][1]);                        \
            pk[m_][1] = cvt_pk(acc[m_][2], acc[m_][3]);                        \
        }                                                                      \
        _Pragma("unroll") for (int s2_ = 0; s2_ < 2; ++s2_) {                  \
            V16 pb;                                                            \
            _Pragma("unroll") for (int u_ = 0; u_ < 4; ++u_) {                 \
                int srcl_ = ((2 * (g & 1) + (u_ >> 1)) << 4) | r;              \
                unsigned lo_ = (unsigned)__shfl((int)pk[2 * s2_][u_ & 1], srcl_, 64);     \
                unsigned hi_ = (unsigned)__shfl((int)pk[2 * s2_ + 1][u_ & 1], srcl_, 64); \
                pb.u[u_] = (g >= 2) ? hi_ : lo_;                               \
            }                                                                  \
            V16 va0_; va0_.u4 = vau[0 * 2 + s2_];                              \
            V16 va1_; va1_.u4 = vau[1 * 2 + s2_];                              \
            __builtin_amdgcn_s_setprio(1);                                     \
            o[0] = mfma16(va0_.b8, pb.b8, o[0]);                               \
            o[1] = mfma16(va1_.b8, pb.b8, o[1]);                               \
            __builtin_amdgcn_s_setprio(0);                                     \
        }                                                                      \
    }

    for (int kt = 0; kt < 16; kt += 2) {
        PHASE(KA, BA, kt * 64, KB, BB, (kt + 1) * 64)
        int kv2 = (kt + 2 < 16) ? (kt + 2) * 64 : 0;
        PHASE(KB, BB, (kt + 1) * 64, KA, BA, kv2)
    }

    // ---- epilogue: normalize, fused gate, store og as bf16 ----
    float linv = 1.0f / lst;
    o[0] *= linv;
    o[1] *= linv;

    // gate_w A-frags + gate_b (loaded here to keep main-loop VGPR low)
    bf16x8_t ga[2]; f32x4_t gb4[2];
#pragma unroll
    for (int mc = 0; mc < 2; ++mc) {
        const float* gwp = gate_w + (size_t)(h * 32 + mc * 16 + r) * 32 + g * 8;
        f32x4_t w0 = *(const f32x4_t*)gwp;
        f32x4_t w1 = *(const f32x4_t*)(gwp + 4);
        V16 tmp;
        tmp.u[0] = cvt_pk(w0[0], w0[1]); tmp.u[1] = cvt_pk(w0[2], w0[3]);
        tmp.u[2] = cvt_pk(w1[0], w1[1]); tmp.u[3] = cvt_pk(w1[2], w1[3]);
        ga[mc] = tmp.b8;
        gb4[mc] = *(const f32x4_t*)(gate_b + h * 32 + mc * 16 + g * 4);
    }

    unsigned pkO[2][2];
#pragma unroll
    for (int md = 0; md < 2; ++md) {
        pkO[md][0] = cvt_pk(o[md][0], o[md][1]);
        pkO[md][1] = cvt_pk(o[md][2], o[md][3]);
    }
    V16 ob;
#pragma unroll
    for (int u = 0; u < 4; ++u) {
        int srcl = ((2 * (g & 1) + (u >> 1)) << 4) | r;
        unsigned lo = (unsigned)__shfl((int)pkO[0][u & 1], srcl, 64);
        unsigned hi = (unsigned)__shfl((int)pkO[1][u & 1], srcl, 64);
        ob.u[u] = (g >= 2) ? hi : lo;
    }
    f32x4_t zero = {0.f, 0.f, 0.f, 0.f};
    f32x4_t gacc0 = mfma16(ga[0], ob.b8, zero);
    f32x4_t gacc1 = mfma16(ga[1], ob.b8, zero);
#pragma unroll
    for (int e = 0; e < 4; ++e) {
        float s0 = 1.0f / (1.0f + __expf(-(gacc0[e] + gb4[0][e])));
        float s1 = 1.0f / (1.0f + __expf(-(gacc1[e] + gb4[1][e])));
        o[0][e] *= s0;
        o[1][e] *= s1;
    }
    unsigned* ogp = (unsigned*)ogb;
#pragma unroll
    for (int md = 0; md < 2; ++md) {
        uint2 st;
        st.x = cvt_pk(o[md][0], o[md][1]);
        st.y = cvt_pk(o[md][2], o[md][3]);
        *(uint2*)&ogp[((size_t)(hb * 1024 + q0 + r)) * 16 + md * 8 + g * 2] = st;
    }
}

// ---------------- K3: out-proj + residual + layernorm via MFMA ----------------
// grid 512, block 512 = 8 waves; block = 16m x 256n, wave = 16m x 32n.
__global__ __launch_bounds__(512) void proj_ln_mfma(
    const unsigned short* __restrict__ ogb, const float* __restrict__ x,
    const unsigned short* __restrict__ wob, const float* __restrict__ bo,
    const float* __restrict__ ln_g, const float* __restrict__ ln_b,
    float* __restrict__ out)
{
    __shared__ float s1l[8][16];
    __shared__ float s2l[8][16];
    const int t = threadIdx.x;
    const int lane = t & 63, w = t >> 6;
    const int r = lane & 15, g = lane >> 4;
    const int m0 = blockIdx.x * 16;
    const int bs = m0 >> 10, l0 = m0 & 1023;
    const int n0 = w * 32;

    const uint4* ap = (const uint4*)ogb;
    const uint4* bp = (const uint4*)wob;

    f32x4_t acc[2] = {};
#pragma unroll
    for (int kt = 0; kt < 8; ++kt) {
        V16 a0, b0, b1;
        a0.u4 = ap[((size_t)(bs * 8 + kt) * 1024 + l0 + r) * 4 + g];
        b0.u4 = bp[(n0 + r) * 32 + kt * 4 + g];
        b1.u4 = bp[(n0 + 16 + r) * 32 + kt * 4 + g];
        acc[0] = mfma16(a0.b8, b0.b8, acc[0]);
        acc[1] = mfma16(a0.b8, b1.b8, acc[1]);
    }

    float bo0 = bo[n0 + r], bo1 = bo[n0 + 16 + r];
#pragma unroll
    for (int e = 0; e < 4; ++e) {
        int m = m0 + g * 4 + e;
        acc[0][e] += bo0 + x[(size_t)m * 256 + n0 + r];
        acc[1][e] += bo1 + x[(size_t)m * 256 + n0 + 16 + r];
    }
    // per-lane partial row sums over this wave's 32 cols
#pragma unroll
    for (int e = 0; e < 4; ++e) {
        float sm = acc[0][e] + acc[1][e];
        float sq = acc[0][e] * acc[0][e] + acc[1][e] * acc[1][e];
        sm += __shfl_xor(sm, 1, 64); sq += __shfl_xor(sq, 1, 64);
        sm += __shfl_xor(sm, 2, 64); sq += __shfl_xor(sq, 2, 64);
        sm += __shfl_xor(sm, 4, 64); sq += __shfl_xor(sq, 4, 64);
        sm += __shfl_xor(sm, 8, 64); sq += __shfl_xor(sq, 8, 64);
        if (r == 0) { s1l[w][g * 4 + e] = sm; s2l[w][g * 4 + e] = sq; }
    }
    __syncthreads();

    float g0 = ln_g[n0 + r], g1 = ln_g[n0 + 16 + r];
    float b0 = ln_b[n0 + r], b1 = ln_b[n0 + 16 + r];
#pragma unroll
    for (int e = 0; e < 4; ++e) {
        int mloc = g * 4 + e;
        float sm = 0.f, sq = 0.f;
#pragma unroll
        for (int wv = 0; wv < 8; ++wv) { sm += s1l[wv][mloc]; sq += s2l[wv][mloc]; }
        float mu = sm * (1.0f / 256.0f);
        float var = sq * (1.0f / 256.0f) - mu * mu;
        float rs = rsqrtf(var + 1e-5f);
        int m = m0 + mloc;
        out[(size_t)m * 256 + n0 + r]      = (acc[0][e] - mu) * rs * g0 + b0;
        out[(size_t)m * 256 + n0 + 16 + r] = (acc[1][e] - mu) * rs * g1 + b1;
    }
}

extern "C" void kernel_launch(void* const* d_in, const int* in_sizes, int n_in,
                              void* d_out, int out_size, void* d_ws, size_t ws_size,
                              hipStream_t stream)
{
    (void)in_sizes; (void)n_in; (void)out_size; (void)ws_size;
    const float* x      = (const float*)d_in[0];
    const float* bulk   = (const float*)d_in[1];
    const float* Wq     = (const float*)d_in[2];
    const float* bq     = (const float*)d_in[3];
    const float* Wk     = (const float*)d_in[4];
    const float* bk     = (const float*)d_in[5];
    const float* Wv     = (const float*)d_in[6];
    const float* bv     = (const float*)d_in[7];
    const float* Wo     = (const float*)d_in[8];
    const float* bo     = (const float*)d_in[9];
    const float* conv_w = (const float*)d_in[10];
    const float* conv_b = (const float*)d_in[11];
    const float* gate_w = (const float*)d_in[12];
    const float* gate_b = (const float*)d_in[13];
    const float* ln_g   = (const float*)d_in[14];
    const float* ln_b   = (const float*)d_in[15];
    float* out = (float*)d_out;

    char* ws = (char*)d_ws;
    unsigned short* xb    = (unsigned short*)ws;                  // 4 MB
    unsigned short* bulkb = (unsigned short*)(ws + (4u << 20));   // 4 MB
    unsigned short* wb    = (unsigned short*)(ws + (8u << 20));   // 512 KB (4 x 256x256)
    unsigned short* qws   = (unsigned short*)(ws + (8u << 20) + (512u << 10)); // 4 MB
    unsigned short* kws   = qws + 2097152;                        // 4 MB
    unsigned short* vws   = qws + 4194304;                        // 4 MB
    unsigned short* vT    = qws + 6291456;                        // 4 MB
    unsigned short* ogb   = vws;  // alias: vws dead after transpose_v (stream-ordered)
    unsigned short* wob   = wb + 3 * 65536;

    conv_bf16<<<dim3(2048, 6), 256, 0, stream>>>(x, bulk, Wq, Wk, Wv, Wo, xb, bulkb, wb);
    qkv_mfma<<<dim3(128, 12), 256, 0, stream>>>(xb, wb, bq, bk, bv, qws, kws, vws);
    transpose_v<<<dim3(4, 64), 256, 0, stream>>>(vws, vT);
    attn_mfma<<<dim3(32, 16), 512, 0, stream>>>(qws, kws, vT, bulkb, conv_w, conv_b,
                                                gate_w, gate_b, ogb);
    proj_ln_mfma<<<512, 512, 0, stream>>>(ogb, x, wob, bo, ln_g, ln_b, out);
}

// Round 6
// 121.861 us; speedup vs baseline: 1.1125x; 1.1115x over previous
//
#include <hip/hip_runtime.h>
#include <hip/hip_bf16.h>

#define C_ 256
#define H_ 8
#define DH_ 32
#define L_ 1024

typedef __bf16 bf16x8_t __attribute__((ext_vector_type(8)));
typedef float f32x4_t __attribute__((ext_vector_type(4)));

union V16 {
    uint4 u4;
    bf16x8_t b8;
    f32x4_t f4;
    unsigned u[4];
};

__device__ __forceinline__ unsigned cvt_pk(float lo, float hi) {
    unsigned r;
    asm volatile("v_cvt_pk_bf16_f32 %0, %1, %2" : "=v"(r) : "v"(lo), "v"(hi));
    return r;
}

__device__ __forceinline__ f32x4_t mfma16(bf16x8_t a, bf16x8_t b, f32x4_t c) {
    return __builtin_amdgcn_mfma_f32_16x16x32_bf16(a, b, c, 0, 0, 0);
}

__device__ __forceinline__ unsigned short f2bf(float f) {
    unsigned u = __float_as_uint(f);
    u += 0x7fffu + ((u >> 16) & 1u);
    return (unsigned short)(u >> 16);
}

__device__ __forceinline__ float bfup(unsigned short u) {
    return __uint_as_float((unsigned)u << 16);
}
__device__ __forceinline__ float bflo(unsigned u) { return __uint_as_float(u << 16); }
__device__ __forceinline__ float bfhi(unsigned u) { return __uint_as_float(u & 0xffff0000u); }
__device__ __forceinline__ float ex2(float x) { return __builtin_amdgcn_exp2f(x); }

#define LOG2E_F 1.4426950408889634f

// ---------------- K0: convert x, bulk, weights -> bf16 ----------------
__global__ __launch_bounds__(256) void conv_bf16(
    const float* __restrict__ x, const float* __restrict__ bulk,
    const float* __restrict__ Wq, const float* __restrict__ Wk,
    const float* __restrict__ Wv, const float* __restrict__ Wo,
    unsigned short* __restrict__ xb, unsigned short* __restrict__ bulkb,
    unsigned short* __restrict__ wb)
{
    int ysel = blockIdx.y;
    const float* src; unsigned short* dst; int n4;
    if (ysel == 0)      { src = x;    dst = xb;    n4 = 524288; }
    else if (ysel == 1) { src = bulk; dst = bulkb; n4 = 524288; }
    else {
        src = (ysel == 2) ? Wq : (ysel == 3) ? Wk : (ysel == 4) ? Wv : Wo;
        dst = wb + (ysel - 2) * 65536; n4 = 16384;
    }
    int i = blockIdx.x * 256 + threadIdx.x;
    if (i >= n4) return;
    float4 v = ((const float4*)src)[i];
    ushort4 o;
    o.x = f2bf(v.x); o.y = f2bf(v.y); o.z = f2bf(v.z); o.w = f2bf(v.w);
    ((ushort4*)dst)[i] = o;
}

// ---------------- K1: QKV projection via MFMA (A = W rows, B = x rows) ----------------
// grid (128, 12), block 256 = 4 waves; wave = 32 tokens x 32 channels, K=256.
// D[wi][mi]: col r = token, row g*4+e = channel -> lane owns 4 consecutive channels.
__global__ __launch_bounds__(256) void qkv_mfma(
    const unsigned short* __restrict__ xb, const unsigned short* __restrict__ wb,
    const float* __restrict__ bq, const float* __restrict__ bk, const float* __restrict__ bv,
    unsigned short* __restrict__ qws, unsigned short* __restrict__ kws,
    unsigned short* __restrict__ vws)
{
    const int t = threadIdx.x;
    const int lane = t & 63, w = t >> 6;
    const int r = lane & 15, g = lane >> 4;
    const int m0 = blockIdx.x * 64 + (w >> 1) * 32;       // token base
    const int n0g = blockIdx.y * 64 + (w & 1) * 32;       // global channel base
    const int z = n0g >> 8, nl = n0g & 255;

    const uint4* ap = (const uint4*)xb;
    const uint4* bp = (const uint4*)(wb + z * 65536);

    f32x4_t acc[2][2] = {};
#pragma unroll
    for (int kt = 0; kt < 8; ++kt) {
        V16 w0, w1, x0, x1;
        w0.u4 = bp[(nl + r) * 32 + kt * 4 + g];
        w1.u4 = bp[(nl + 16 + r) * 32 + kt * 4 + g];
        x0.u4 = ap[(m0 + r) * 32 + kt * 4 + g];
        x1.u4 = ap[(m0 + 16 + r) * 32 + kt * 4 + g];
        acc[0][0] = mfma16(w0.b8, x0.b8, acc[0][0]);
        acc[0][1] = mfma16(w0.b8, x1.b8, acc[0][1]);
        acc[1][0] = mfma16(w1.b8, x0.b8, acc[1][0]);
        acc[1][1] = mfma16(w1.b8, x1.b8, acc[1][1]);
    }

    const float* bias = (z == 0) ? bq : (z == 1) ? bk : bv;
    unsigned short* dst = (z == 0) ? qws : (z == 1) ? kws : vws;
    const float sc = (z == 0) ? (0.17677669529663687f * LOG2E_F) : 1.0f;
#pragma unroll
    for (int wi = 0; wi < 2; ++wi) {
        f32x4_t b4 = *(const f32x4_t*)&bias[nl + wi * 16 + g * 4];
        int nc = nl + wi * 16 + g * 4;
        int h = nc >> 5, d0 = nc & 31;
#pragma unroll
        for (int mi = 0; mi < 2; ++mi) {
            int tok = m0 + mi * 16 + r;
            int bs = tok >> 10, l = tok & 1023;
            float v0 = (acc[wi][mi][0] + b4[0]) * sc;
            float v1 = (acc[wi][mi][1] + b4[1]) * sc;
            float v2 = (acc[wi][mi][2] + b4[2]) * sc;
            float v3 = (acc[wi][mi][3] + b4[3]) * sc;
            uint2 st;
            st.x = cvt_pk(v0, v1);
            st.y = cvt_pk(v2, v3);
            *(uint2*)&dst[((size_t)((bs * H_ + h) * L_ + l)) * DH_ + d0] = st;
        }
    }
}

// ---------------- K1b: transpose V per head: [hb][l][d] -> [hb][d][l] ----------------
__global__ __launch_bounds__(256) void transpose_v(const unsigned short* __restrict__ vws,
                                                   unsigned short* __restrict__ vT)
{
    __shared__ unsigned short tile[32][264];
    int hb = blockIdx.y;
    int l0 = blockIdx.x * 256;
    int t = threadIdx.x;
    const unsigned* src = (const unsigned*)(vws + (size_t)hb * 32768) + l0 * 16;
    for (int i = t; i < 4096; i += 256) {
        int l = i >> 4, d2 = i & 15;
        unsigned u = src[i];
        tile[d2 * 2][l]     = (unsigned short)(u & 0xffffu);
        tile[d2 * 2 + 1][l] = (unsigned short)(u >> 16);
    }
    __syncthreads();
    unsigned* dst = (unsigned*)(vT + (size_t)hb * 32768);
    int d = t >> 3, seg = (t & 7) * 32;
#pragma unroll
    for (int j = 0; j < 16; ++j) {
        int l = seg + j * 2;
        unsigned u = (unsigned)tile[d][l] | ((unsigned)tile[d][l + 1] << 16);
        dst[d * 512 + (l0 + l) / 2] = u;
    }
}

// ---------------- K2: MFMA flash attention, kv-split, base-2 exponent space ----------------
// grid (16, 2, 16): x = 64q tile, y = kv half, z = (b,h). block 512 = 4 tracks x 2 q-halves.
// Each wave: 32 q (2 n-frags, independent softmax chains) x 512 kv (8 phases of 64).
__global__ __launch_bounds__(512, 4) void attn_mfma(
    const unsigned short* __restrict__ qws, const unsigned short* __restrict__ kws,
    const unsigned short* __restrict__ vT, const unsigned short* __restrict__ bulkb,
    const float* __restrict__ conv_w, const float* __restrict__ conv_b,
    uint4* __restrict__ partO, float2* __restrict__ ml)
{
    const int t = threadIdx.x;
    const int lane = t & 63, w = t >> 6;
    const int g = lane >> 4, r = lane & 15;
    const int s = w & 3, qh = w >> 2;
    const int h = blockIdx.z & 7, b = blockIdx.z >> 3;
    const int half = blockIdx.y;
    const int hb = (b * 4 + s) * 8 + h;
    const int q0 = blockIdx.x * 64 + qh * 32;

    const uint4* kp = (const uint4*)(kws + (size_t)hb * 32768);
    const uint4* qp = (const uint4*)(qws + (size_t)hb * 32768);
    const uint4* vp = (const uint4*)(vT  + (size_t)hb * 32768);
    const ushort4* bp4 = (const ushort4*)(bulkb + (size_t)b * 1048576);
    const float cw2 = conv_w[h] * LOG2E_F, cb2 = conv_b[h] * LOG2E_F;

    bf16x8_t qb[2];
#pragma unroll
    for (int n = 0; n < 2; ++n) {
        V16 tmp; tmp.u4 = qp[(q0 + n * 16 + r) * 4 + g];
        qb[n] = tmp.b8;
    }

    f32x4_t o[2][2] = {};                  // [md][n]; row d = md*16+g*4+e, col q = n*16+r
    float mst[2] = {-3.0e38f, -3.0e38f};
    float lst[2] = {0.f, 0.f};

    const int kbase = half * 512;
    for (int kt = 0; kt < 8; ++kt) {
        const int kv0 = kbase + kt * 64;
        bf16x8_t ka[4];
#pragma unroll
        for (int m = 0; m < 4; ++m) {
            V16 tmp; tmp.u4 = kp[(kv0 + m * 16 + r) * 4 + g];
            ka[m] = tmp.b8;
        }
        uint4 vau[4];
#pragma unroll
        for (int md = 0; md < 2; ++md)
#pragma unroll
            for (int s2 = 0; s2 < 2; ++s2)
                vau[md * 2 + s2] = vp[(md * 16 + r) * 128 + (kv0 >> 3) + s2 * 4 + g];

        f32x4_t acc[4][2];
#pragma unroll
        for (int n = 0; n < 2; ++n)
#pragma unroll
            for (int m = 0; m < 4; ++m) {
                ushort4 bb = bp4[(size_t)(q0 + n * 16 + r) * 256 + ((kv0 + m * 16) >> 2) + g];
                f32x4_t b4;
                b4[0] = bfup(bb.x); b4[1] = bfup(bb.y);
                b4[2] = bfup(bb.z); b4[3] = bfup(bb.w);
                acc[m][n] = cw2 * b4 + cb2;
            }
        __builtin_amdgcn_s_setprio(1);
#pragma unroll
        for (int m = 0; m < 4; ++m)
#pragma unroll
            for (int n = 0; n < 2; ++n)
                acc[m][n] = mfma16(ka[m], qb[n], acc[m][n]);
        __builtin_amdgcn_s_setprio(0);

#pragma unroll
        for (int n = 0; n < 2; ++n) {
            // --- max (tree, max3-fusable) ---
            float x0 = fmaxf(fmaxf(acc[0][n][0], acc[0][n][1]), fmaxf(acc[0][n][2], acc[0][n][3]));
            float x1 = fmaxf(fmaxf(acc[1][n][0], acc[1][n][1]), fmaxf(acc[1][n][2], acc[1][n][3]));
            float x2 = fmaxf(fmaxf(acc[2][n][0], acc[2][n][1]), fmaxf(acc[2][n][2], acc[2][n][3]));
            float x3 = fmaxf(fmaxf(acc[3][n][0], acc[3][n][1]), fmaxf(acc[3][n][2], acc[3][n][3]));
            float pmax = fmaxf(fmaxf(x0, x1), fmaxf(x2, x3));
            pmax = fmaxf(pmax, __shfl_xor(pmax, 16, 64));
            pmax = fmaxf(pmax, __shfl_xor(pmax, 32, 64));
            // --- defer-max (threshold in base-2) ---
            if (!__all(pmax <= mst[n] + 11.0f)) {
                float mnew = fmaxf(mst[n], pmax);
                float scl = ex2(mst[n] - mnew);
                mst[n] = mnew; lst[n] *= scl;
                o[0][n] *= scl; o[1][n] *= scl;
            }
            // --- p = 2^(s - m), sum (tree) ---
#pragma unroll
            for (int m = 0; m < 4; ++m)
#pragma unroll
                for (int e = 0; e < 4; ++e)
                    acc[m][n][e] = ex2(acc[m][n][e] - mst[n]);
            float s0 = (acc[0][n][0] + acc[0][n][1]) + (acc[0][n][2] + acc[0][n][3]);
            float s1 = (acc[1][n][0] + acc[1][n][1]) + (acc[1][n][2] + acc[1][n][3]);
            float s2 = (acc[2][n][0] + acc[2][n][1]) + (acc[2][n][2] + acc[2][n][3]);
            float s3 = (acc[3][n][0] + acc[3][n][1]) + (acc[3][n][2] + acc[3][n][3]);
            float psum = (s0 + s1) + (s2 + s3);
            psum += __shfl_xor(psum, 16, 64);
            psum += __shfl_xor(psum, 32, 64);
            lst[n] += psum;
            // --- pack P, redistribute to P^T B-frags, PV ---
            unsigned pk[4][2];
#pragma unroll
            for (int m = 0; m < 4; ++m) {
                pk[m][0] = cvt_pk(acc[m][n][0], acc[m][n][1]);
                pk[m][1] = cvt_pk(acc[m][n][2], acc[m][n][3]);
            }
#pragma unroll
            for (int s2_ = 0; s2_ < 2; ++s2_) {
                V16 pb;
#pragma unroll
                for (int u = 0; u < 4; ++u) {
                    int srcl = ((2 * (g & 1) + (u >> 1)) << 4) | r;
                    unsigned lo = (unsigned)__shfl((int)pk[2 * s2_][u & 1], srcl, 64);
                    unsigned hi = (unsigned)__shfl((int)pk[2 * s2_ + 1][u & 1], srcl, 64);
                    pb.u[u] = (g >= 2) ? hi : lo;
                }
                V16 va0; va0.u4 = vau[0 * 2 + s2_];
                V16 va1; va1.u4 = vau[1 * 2 + s2_];
                __builtin_amdgcn_s_setprio(1);
                o[0][n] = mfma16(va0.b8, pb.b8, o[0][n]);
                o[1][n] = mfma16(va1.b8, pb.b8, o[1][n]);
                __builtin_amdgcn_s_setprio(0);
            }
        }
    }

    // ---- store partials (Oacc bf16, m/l f32) ----
    const int qt = q0 >> 5;
#pragma unroll
    for (int n = 0; n < 2; ++n) {
        uint4 st;
        st.x = cvt_pk(o[0][n][0], o[0][n][1]);
        st.y = cvt_pk(o[0][n][2], o[0][n][3]);
        st.z = cvt_pk(o[1][n][0], o[1][n][1]);
        st.w = cvt_pk(o[1][n][2], o[1][n][3]);
        partO[((((size_t)hb * 2 + half) * 32 + qt) * 2 + n) * 64 + lane] = st;
        if (g == 0)
            ml[((size_t)hb * 2 + half) * 1024 + q0 + n * 16 + r] = make_float2(mst[n], lst[n]);
    }
}

// ---------------- K2b: combine kv-halves + fused gate -> ogb ----------------
// grid 256, block 512 = 8 waves; wave = one (hb, 32q tile).
__global__ __launch_bounds__(512) void attn_combine(
    const uint4* __restrict__ partO, const float2* __restrict__ ml,
    const float* __restrict__ gate_w, const float* __restrict__ gate_b,
    unsigned short* __restrict__ ogb)
{
    const int t = threadIdx.x, lane = t & 63, w = t >> 6;
    const int g = lane >> 4, r = lane & 15;
    const int widx = blockIdx.x * 8 + w;     // 0..2047
    const int hb = widx >> 5, qt = widx & 31;
    const int q0 = qt * 32, h = hb & 7;

    f32x4_t o[2][2];
#pragma unroll
    for (int n = 0; n < 2; ++n) {
        uint4 p0 = partO[((((size_t)hb * 2 + 0) * 32 + qt) * 2 + n) * 64 + lane];
        uint4 p1 = partO[((((size_t)hb * 2 + 1) * 32 + qt) * 2 + n) * 64 + lane];
        float2 ab0 = ml[((size_t)hb * 2 + 0) * 1024 + q0 + n * 16 + r];
        float2 ab1 = ml[((size_t)hb * 2 + 1) * 1024 + q0 + n * 16 + r];
        float M = fmaxf(ab0.x, ab1.x);
        float w0 = ex2(ab0.x - M), w1 = ex2(ab1.x - M);
        float li = 1.0f / (ab0.y * w0 + ab1.y * w1);
        float w0l = w0 * li, w1l = w1 * li;
        o[0][n][0] = bflo(p0.x) * w0l + bflo(p1.x) * w1l;
        o[0][n][1] = bfhi(p0.x) * w0l + bfhi(p1.x) * w1l;
        o[0][n][2] = bflo(p0.y) * w0l + bflo(p1.y) * w1l;
        o[0][n][3] = bfhi(p0.y) * w0l + bfhi(p1.y) * w1l;
        o[1][n][0] = bflo(p0.z) * w0l + bflo(p1.z) * w1l;
        o[1][n][1] = bfhi(p0.z) * w0l + bfhi(p1.z) * w1l;
        o[1][n][2] = bflo(p0.w) * w0l + bflo(p1.w) * w1l;
        o[1][n][3] = bfhi(p0.w) * w0l + bfhi(p1.w) * w1l;
    }

    // gate_w A-frags + gate_b
    bf16x8_t ga[2]; f32x4_t gb4[2];
#pragma unroll
    for (int mc = 0; mc < 2; ++mc) {
        const float* gwp = gate_w + (size_t)(h * 32 + mc * 16 + r) * 32 + g * 8;
        f32x4_t w0 = *(const f32x4_t*)gwp;
        f32x4_t w1 = *(const f32x4_t*)(gwp + 4);
        V16 tmp;
        tmp.u[0] = cvt_pk(w0[0], w0[1]); tmp.u[1] = cvt_pk(w0[2], w0[3]);
        tmp.u[2] = cvt_pk(w1[0], w1[1]); tmp.u[3] = cvt_pk(w1[2], w1[3]);
        ga[mc] = tmp.b8;
        gb4[mc] = *(const f32x4_t*)(gate_b + h * 32 + mc * 16 + g * 4);
    }

    unsigned* ogp = (unsigned*)ogb;
#pragma unroll
    for (int n = 0; n < 2; ++n) {
        unsigned pkO[2][2];
#pragma unroll
        for (int md = 0; md < 2; ++md) {
            pkO[md][0] = cvt_pk(o[md][n][0], o[md][n][1]);
            pkO[md][1] = cvt_pk(o[md][n][2], o[md][n][3]);
        }
        V16 ob;
#pragma unroll
        for (int u = 0; u < 4; ++u) {
            int srcl = ((2 * (g & 1) + (u >> 1)) << 4) | r;
            unsigned lo = (unsigned)__shfl((int)pkO[0][u & 1], srcl, 64);
            unsigned hi = (unsigned)__shfl((int)pkO[1][u & 1], srcl, 64);
            ob.u[u] = (g >= 2) ? hi : lo;
        }
        f32x4_t zero = {0.f, 0.f, 0.f, 0.f};
        f32x4_t gacc0 = mfma16(ga[0], ob.b8, zero);
        f32x4_t gacc1 = mfma16(ga[1], ob.b8, zero);
#pragma unroll
        for (int e = 0; e < 4; ++e) {
            float sg0 = 1.0f / (1.0f + __expf(-(gacc0[e] + gb4[0][e])));
            float sg1 = 1.0f / (1.0f + __expf(-(gacc1[e] + gb4[1][e])));
            o[0][n][e] *= sg0;
            o[1][n][e] *= sg1;
        }
#pragma unroll
        for (int md = 0; md < 2; ++md) {
            uint2 st;
            st.x = cvt_pk(o[md][n][0], o[md][n][1]);
            st.y = cvt_pk(o[md][n][2], o[md][n][3]);
            *(uint2*)&ogp[((size_t)(hb * 1024 + q0 + n * 16 + r)) * 16 + md * 8 + g * 2] = st;
        }
    }
}

// ---------------- K3: out-proj + residual + layernorm via MFMA ----------------
__global__ __launch_bounds__(512) void proj_ln_mfma(
    const unsigned short* __restrict__ ogb, const float* __restrict__ x,
    const unsigned short* __restrict__ wob, const float* __restrict__ bo,
    const float* __restrict__ ln_g, const float* __restrict__ ln_b,
    float* __restrict__ out)
{
    __shared__ float s1l[8][16];
    __shared__ float s2l[8][16];
    const int t = threadIdx.x;
    const int lane = t & 63, w = t >> 6;
    const int r = lane & 15, g = lane >> 4;
    const int m0 = blockIdx.x * 16;
    const int bs = m0 >> 10, l0 = m0 & 1023;
    const int n0 = w * 32;

    const uint4* ap = (const uint4*)ogb;
    const uint4* bp = (const uint4*)wob;

    f32x4_t acc[2] = {};
#pragma unroll
    for (int kt = 0; kt < 8; ++kt) {
        V16 a0, b0, b1;
        a0.u4 = ap[((size_t)(bs * 8 + kt) * 1024 + l0 + r) * 4 + g];
        b0.u4 = bp[(n0 + r) * 32 + kt * 4 + g];
        b1.u4 = bp[(n0 + 16 + r) * 32 + kt * 4 + g];
        acc[0] = mfma16(a0.b8, b0.b8, acc[0]);
        acc[1] = mfma16(a0.b8, b1.b8, acc[1]);
    }

    float bo0 = bo[n0 + r], bo1 = bo[n0 + 16 + r];
#pragma unroll
    for (int e = 0; e < 4; ++e) {
        int m = m0 + g * 4 + e;
        acc[0][e] += bo0 + x[(size_t)m * 256 + n0 + r];
        acc[1][e] += bo1 + x[(size_t)m * 256 + n0 + 16 + r];
    }
#pragma unroll
    for (int e = 0; e < 4; ++e) {
        float sm = acc[0][e] + acc[1][e];
        float sq = acc[0][e] * acc[0][e] + acc[1][e] * acc[1][e];
        sm += __shfl_xor(sm, 1, 64); sq += __shfl_xor(sq, 1, 64);
        sm += __shfl_xor(sm, 2, 64); sq += __shfl_xor(sq, 2, 64);
        sm += __shfl_xor(sm, 4, 64); sq += __shfl_xor(sq, 4, 64);
        sm += __shfl_xor(sm, 8, 64); sq += __shfl_xor(sq, 8, 64);
        if (r == 0) { s1l[w][g * 4 + e] = sm; s2l[w][g * 4 + e] = sq; }
    }
    __syncthreads();

    float g0 = ln_g[n0 + r], g1 = ln_g[n0 + 16 + r];
    float b0 = ln_b[n0 + r], b1 = ln_b[n0 + 16 + r];
#pragma unroll
    for (int e = 0; e < 4; ++e) {
        int mloc = g * 4 + e;
        float sm = 0.f, sq = 0.f;
#pragma unroll
        for (int wv = 0; wv < 8; ++wv) { sm += s1l[wv][mloc]; sq += s2l[wv][mloc]; }
        float mu = sm * (1.0f / 256.0f);
        float var = sq * (1.0f / 256.0f) - mu * mu;
        float rs = rsqrtf(var + 1e-5f);
        int m = m0 + mloc;
        out[(size_t)m * 256 + n0 + r]      = (acc[0][e] - mu) * rs * g0 + b0;
        out[(size_t)m * 256 + n0 + 16 + r] = (acc[1][e] - mu) * rs * g1 + b1;
    }
}

extern "C" void kernel_launch(void* const* d_in, const int* in_sizes, int n_in,
                              void* d_out, int out_size, void* d_ws, size_t ws_size,
                              hipStream_t stream)
{
    (void)in_sizes; (void)n_in; (void)out_size; (void)ws_size;
    const float* x      = (const float*)d_in[0];
    const float* bulk   = (const float*)d_in[1];
    const float* Wq     = (const float*)d_in[2];
    const float* bq     = (const float*)d_in[3];
    const float* Wk     = (const float*)d_in[4];
    const float* bk     = (const float*)d_in[5];
    const float* Wv     = (const float*)d_in[6];
    const float* bv     = (const float*)d_in[7];
    const float* Wo     = (const float*)d_in[8];
    const float* bo     = (const float*)d_in[9];
    const float* conv_w = (const float*)d_in[10];
    const float* conv_b = (const float*)d_in[11];
    const float* gate_w = (const float*)d_in[12];
    const float* gate_b = (const float*)d_in[13];
    const float* ln_g   = (const float*)d_in[14];
    const float* ln_b   = (const float*)d_in[15];
    float* out = (float*)d_out;

    char* ws = (char*)d_ws;
    unsigned short* xb    = (unsigned short*)ws;                  // 4 MB (dead after qkv)
    unsigned short* bulkb = (unsigned short*)(ws + (4u << 20));   // 4 MB
    unsigned short* wb    = (unsigned short*)(ws + (8u << 20));   // 512 KB
    unsigned short* qws   = (unsigned short*)(ws + (8u << 20) + (512u << 10)); // 4 MB
    unsigned short* kws   = qws + 2097152;                        // 4 MB
    unsigned short* vws   = qws + 4194304;                        // 4 MB (dead after transpose_v)
    unsigned short* vT    = qws + 6291456;                        // 4 MB
    uint4*          partO = (uint4*)(ws + (24u << 20) + (512u << 10)); // 8 MB  -> total 32.5 MB
    float2*         mlp   = (float2*)ws;                          // 1 MB, aliases dead xb
    unsigned short* ogb   = vws;                                  // aliases dead vws
    unsigned short* wob   = wb + 3 * 65536;

    conv_bf16<<<dim3(2048, 6), 256, 0, stream>>>(x, bulk, Wq, Wk, Wv, Wo, xb, bulkb, wb);
    qkv_mfma<<<dim3(128, 12), 256, 0, stream>>>(xb, wb, bq, bk, bv, qws, kws, vws);
    transpose_v<<<dim3(4, 64), 256, 0, stream>>>(vws, vT);
    attn_mfma<<<dim3(16, 2, 16), 512, 0, stream>>>(qws, kws, vT, bulkb, conv_w, conv_b,
                                                   partO, mlp);
    attn_combine<<<256, 512, 0, stream>>>(partO, mlp, gate_w, gate_b, ogb);
    proj_ln_mfma<<<512, 512, 0, stream>>>(ogb, x, wob, bo, ln_g, ln_b, out);
}

// Round 8
// 116.496 us; speedup vs baseline: 1.1637x; 1.0460x over previous
//
#include <hip/hip_runtime.h>
#include <hip/hip_bf16.h>

#define C_ 256
#define H_ 8
#define DH_ 32
#define L_ 1024

typedef __bf16 bf16x8_t __attribute__((ext_vector_type(8)));
typedef float f32x4_t __attribute__((ext_vector_type(4)));
typedef float f32x16_t __attribute__((ext_vector_type(16)));

union V16 {
    uint4 u4;
    bf16x8_t b8;
    f32x4_t f4;
    unsigned u[4];
};

__device__ __forceinline__ unsigned cvt_pk(float lo, float hi) {
    unsigned r;
    asm volatile("v_cvt_pk_bf16_f32 %0, %1, %2" : "=v"(r) : "v"(lo), "v"(hi));
    return r;
}

__device__ __forceinline__ f32x4_t mfma16(bf16x8_t a, bf16x8_t b, f32x4_t c) {
    return __builtin_amdgcn_mfma_f32_16x16x32_bf16(a, b, c, 0, 0, 0);
}
__device__ __forceinline__ f32x16_t mfma32(bf16x8_t a, bf16x8_t b, f32x16_t c) {
    return __builtin_amdgcn_mfma_f32_32x32x16_bf16(a, b, c, 0, 0, 0);
}

// v_permlane32_swap_b32: a_new = {a.lo, b.lo}, b_new = {a.hi, b.hi}.
// ONLY used on genuinely distinct live values (distinct registers guaranteed).
__device__ __forceinline__ void pl32swap(unsigned& a, unsigned& b) {
    asm volatile("v_permlane32_swap_b32 %0, %1" : "+v"(a), "+v"(b));
}

__device__ __forceinline__ unsigned short f2bf(float f) {
    unsigned u = __float_as_uint(f);
    u += 0x7fffu + ((u >> 16) & 1u);
    return (unsigned short)(u >> 16);
}
__device__ __forceinline__ float bflo(unsigned u) { return __uint_as_float(u << 16); }
__device__ __forceinline__ float bfhi(unsigned u) { return __uint_as_float(u & 0xffff0000u); }
__device__ __forceinline__ float ex2(float x) { return __builtin_amdgcn_exp2f(x); }

#define LOG2E_F 1.4426950408889634f

__device__ __forceinline__ float tmax16(const f32x16_t& v) {
    float a = fmaxf(fmaxf(v[0], v[1]), fmaxf(v[2], v[3]));
    float b = fmaxf(fmaxf(v[4], v[5]), fmaxf(v[6], v[7]));
    float c = fmaxf(fmaxf(v[8], v[9]), fmaxf(v[10], v[11]));
    float d = fmaxf(fmaxf(v[12], v[13]), fmaxf(v[14], v[15]));
    return fmaxf(fmaxf(a, b), fmaxf(c, d));
}
__device__ __forceinline__ float tsum16(const f32x16_t& v) {
    float a = (v[0] + v[1]) + (v[2] + v[3]);
    float b = (v[4] + v[5]) + (v[6] + v[7]);
    float c = (v[8] + v[9]) + (v[10] + v[11]);
    float d = (v[12] + v[13]) + (v[14] + v[15]);
    return (a + b) + (c + d);
}

// ---------------- K0: convert x + weights -> bf16 ----------------
// grid (2048, 5): y=0 -> x, y=1..4 -> Wq/Wk/Wv/Wo.
__global__ __launch_bounds__(256) void conv_bf16(
    const float* __restrict__ x,
    const float* __restrict__ Wq, const float* __restrict__ Wk,
    const float* __restrict__ Wv, const float* __restrict__ Wo,
    unsigned short* __restrict__ xb, unsigned short* __restrict__ wb)
{
    int ysel = blockIdx.y;
    const float* src; unsigned short* dst; int n4;
    if (ysel == 0) { src = x; dst = xb; n4 = 524288; }
    else {
        src = (ysel == 1) ? Wq : (ysel == 2) ? Wk : (ysel == 3) ? Wv : Wo;
        dst = wb + (ysel - 1) * 65536; n4 = 16384;
    }
    int i = blockIdx.x * 256 + threadIdx.x;
    if (i >= n4) return;
    float4 v = ((const float4*)src)[i];
    ushort4 o;
    o.x = f2bf(v.x); o.y = f2bf(v.y); o.z = f2bf(v.z); o.w = f2bf(v.w);
    ((ushort4*)dst)[i] = o;
}

// ---------------- K1: QKV projection via MFMA (A = W rows, B = x rows) ----------------
// grid (128, 12), block 256 = 4 waves; wave = 32 tokens x 32 channels, K=256.
__global__ __launch_bounds__(256) void qkv_mfma(
    const unsigned short* __restrict__ xb, const unsigned short* __restrict__ wb,
    const float* __restrict__ bq, const float* __restrict__ bk, const float* __restrict__ bv,
    unsigned short* __restrict__ qws, unsigned short* __restrict__ kws,
    unsigned short* __restrict__ vws)
{
    const int t = threadIdx.x;
    const int lane = t & 63, w = t >> 6;
    const int r = lane & 15, g = lane >> 4;
    const int m0 = blockIdx.x * 64 + (w >> 1) * 32;
    const int n0g = blockIdx.y * 64 + (w & 1) * 32;
    const int z = n0g >> 8, nl = n0g & 255;

    const uint4* ap = (const uint4*)xb;
    const uint4* bp = (const uint4*)(wb + z * 65536);

    f32x4_t acc[2][2] = {};
#pragma unroll
    for (int kt = 0; kt < 8; ++kt) {
        V16 w0, w1, x0, x1;
        w0.u4 = bp[(nl + r) * 32 + kt * 4 + g];
        w1.u4 = bp[(nl + 16 + r) * 32 + kt * 4 + g];
        x0.u4 = ap[(m0 + r) * 32 + kt * 4 + g];
        x1.u4 = ap[(m0 + 16 + r) * 32 + kt * 4 + g];
        acc[0][0] = mfma16(w0.b8, x0.b8, acc[0][0]);
        acc[0][1] = mfma16(w0.b8, x1.b8, acc[0][1]);
        acc[1][0] = mfma16(w1.b8, x0.b8, acc[1][0]);
        acc[1][1] = mfma16(w1.b8, x1.b8, acc[1][1]);
    }

    const float* bias = (z == 0) ? bq : (z == 1) ? bk : bv;
    unsigned short* dst = (z == 0) ? qws : (z == 1) ? kws : vws;
    const float sc = (z == 0) ? (0.17677669529663687f * LOG2E_F) : 1.0f;
#pragma unroll
    for (int wi = 0; wi < 2; ++wi) {
        f32x4_t b4 = *(const f32x4_t*)&bias[nl + wi * 16 + g * 4];
        int nc = nl + wi * 16 + g * 4;
        int h = nc >> 5, d0 = nc & 31;
#pragma unroll
        for (int mi = 0; mi < 2; ++mi) {
            int tok = m0 + mi * 16 + r;
            int bs = tok >> 10, l = tok & 1023;
            float v0 = (acc[wi][mi][0] + b4[0]) * sc;
            float v1 = (acc[wi][mi][1] + b4[1]) * sc;
            float v2 = (acc[wi][mi][2] + b4[2]) * sc;
            float v3 = (acc[wi][mi][3] + b4[3]) * sc;
            uint2 st;
            st.x = cvt_pk(v0, v1);
            st.y = cvt_pk(v2, v3);
            *(uint2*)&dst[((size_t)((bs * H_ + h) * L_ + l)) * DH_ + d0] = st;
        }
    }
}

// ---------------- K1b: transpose V per head: [hb][l][d] -> [hb][d][l] ----------------
__global__ __launch_bounds__(256) void transpose_v(const unsigned short* __restrict__ vws,
                                                   unsigned short* __restrict__ vT)
{
    __shared__ unsigned short tile[32][264];
    int hb = blockIdx.y;
    int l0 = blockIdx.x * 256;
    int t = threadIdx.x;
    const unsigned* src = (const unsigned*)(vws + (size_t)hb * 32768) + l0 * 16;
    for (int i = t; i < 4096; i += 256) {
        int l = i >> 4, d2 = i & 15;
        unsigned u = src[i];
        tile[d2 * 2][l]     = (unsigned short)(u & 0xffffu);
        tile[d2 * 2 + 1][l] = (unsigned short)(u >> 16);
    }
    __syncthreads();
    unsigned* dst = (unsigned*)(vT + (size_t)hb * 32768);
    int d = t >> 3, seg = (t & 7) * 32;
#pragma unroll
    for (int j = 0; j < 16; ++j) {
        int l = seg + j * 2;
        unsigned u = (unsigned)tile[d][l] | ((unsigned)tile[d][l + 1] << 16);
        dst[d * 512 + (l0 + l) / 2] = u;
    }
}

// ---------------- K2: 32x32-MFMA flash attention, permlane redistribution ----------------
// grid (16, 2, 16): x = 64q tile, y = kv half, z = (b,h). block 512 = 4 tracks x 2 q-halves.
// Wave = 32 q; S^T tile: col q = lane&31, row kv = (e&3)+8*(e>>2)+4*hi.
__global__ __launch_bounds__(512, 4) void attn_mfma(
    const unsigned short* __restrict__ qws, const unsigned short* __restrict__ kws,
    const unsigned short* __restrict__ vT, const float* __restrict__ bulk,
    const float* __restrict__ conv_w, const float* __restrict__ conv_b,
    uint4* __restrict__ partO, float2* __restrict__ ml)
{
    const int t = threadIdx.x;
    const int lane = t & 63, w = t >> 6;
    const int la = lane & 31, hi = lane >> 5;
    const int s = w & 3, qh = w >> 2;
    const int h = blockIdx.z & 7, b = blockIdx.z >> 3;
    const int half = blockIdx.y;
    const int hb = (b * 4 + s) * 8 + h;
    const int q0 = blockIdx.x * 64 + qh * 32;

    const uint4* kp = (const uint4*)(kws + (size_t)hb * 32768);
    const uint4* qp = (const uint4*)(qws + (size_t)hb * 32768);
    const uint4* vp = (const uint4*)(vT  + (size_t)hb * 32768) + la * 128 + hi + (half << 6);
    const float* bulkp = bulk + (size_t)b * 1048576 + (size_t)(q0 + la) * 1024 + 4 * hi + half * 512;
    const float cw2 = conv_w[h] * LOG2E_F, cb2 = conv_b[h] * LOG2E_F;

    // Q B-frags (held whole kernel): Q[q0+la][t16*16 + hi*8 + j]
    bf16x8_t qb0, qb1;
    { V16 m; m.u4 = qp[(q0 + la) * 4 + hi];     qb0 = m.b8; }
    { V16 m; m.u4 = qp[(q0 + la) * 4 + 2 + hi]; qb1 = m.b8; }

    f32x16_t o = {};            // O^T: row d = (e&3)+8*(e>>2)+4*hi, col q = la
    float mst = -3.0e38f, lst = 0.f;

    const int kvbase = half * 512;
    for (int kt = 0; kt < 8; ++kt) {
        const int kvA = kvbase + kt * 64;
        // K A-frags: K[kv + la][t16*16 + hi*8 + j]
        bf16x8_t kA0, kA1, kB0, kB1;
        { V16 m; m.u4 = kp[(kvA + la) * 4 + hi];          kA0 = m.b8; }
        { V16 m; m.u4 = kp[(kvA + la) * 4 + 2 + hi];      kA1 = m.b8; }
        { V16 m; m.u4 = kp[(kvA + 32 + la) * 4 + hi];     kB0 = m.b8; }
        { V16 m; m.u4 = kp[(kvA + 32 + la) * 4 + 2 + hi]; kB1 = m.b8; }
        // V^T A-frags: vT[la][kv0 + tpv*16 + hi*8 + j]
        V16 v0, v1, v2, v3;
        v0.u4 = vp[kt * 8];
        v1.u4 = vp[kt * 8 + 2];
        v2.u4 = vp[kt * 8 + 4];
        v3.u4 = vp[kt * 8 + 6];
        // bias init (f32 direct): acc[e] row kv block = 8a + 4hi (+32 tile B)
        f32x16_t accA, accB;
#pragma unroll
        for (int a = 0; a < 4; ++a) {
            f32x4_t ba = *(const f32x4_t*)(bulkp + kt * 64 + 8 * a);
            f32x4_t bb = *(const f32x4_t*)(bulkp + kt * 64 + 32 + 8 * a);
#pragma unroll
            for (int i = 0; i < 4; ++i) {
                accA[4 * a + i] = cw2 * ba[i] + cb2;
                accB[4 * a + i] = cw2 * bb[i] + cb2;
            }
        }
        __builtin_amdgcn_s_setprio(1);
        accA = mfma32(kA0, qb0, accA);
        accA = mfma32(kA1, qb1, accA);
        accB = mfma32(kB0, qb0, accB);
        accB = mfma32(kB1, qb1, accB);
        __builtin_amdgcn_s_setprio(0);

        // --- online softmax (base-2); cross-half reduce via proven shfl_xor ---
        float pmax = fmaxf(tmax16(accA), tmax16(accB));
        pmax = fmaxf(pmax, __shfl_xor(pmax, 32, 64));
        if (!__all(pmax <= mst + 8.0f)) {
            float mnew = fmaxf(mst, pmax);
            float scl = ex2(mst - mnew);
            mst = mnew; lst *= scl;
            o *= scl;
        }
#pragma unroll
        for (int e = 0; e < 16; ++e) {
            accA[e] = ex2(accA[e] - mst);
            accB[e] = ex2(accB[e] - mst);
        }
        float psum = tsum16(accA) + tsum16(accB);
        psum += __shfl_xor(psum, 32, 64);
        lst += psum;

        // --- pack P -> bf16 words, permlane-swap into B-frags ---
        unsigned pkA[4][2], pkB[4][2];
#pragma unroll
        for (int a = 0; a < 4; ++a) {
            pkA[a][0] = cvt_pk(accA[4 * a], accA[4 * a + 1]);
            pkA[a][1] = cvt_pk(accA[4 * a + 2], accA[4 * a + 3]);
            pkB[a][0] = cvt_pk(accB[4 * a], accB[4 * a + 1]);
            pkB[a][1] = cvt_pk(accB[4 * a + 2], accB[4 * a + 3]);
        }
        pl32swap(pkA[0][0], pkA[1][0]); pl32swap(pkA[0][1], pkA[1][1]);
        pl32swap(pkA[2][0], pkA[3][0]); pl32swap(pkA[2][1], pkA[3][1]);
        pl32swap(pkB[0][0], pkB[1][0]); pl32swap(pkB[0][1], pkB[1][1]);
        pl32swap(pkB[2][0], pkB[3][0]); pl32swap(pkB[2][1], pkB[3][1]);
        V16 pA0, pA1, pB0, pB1;
        pA0.u[0] = pkA[0][0]; pA0.u[1] = pkA[0][1]; pA0.u[2] = pkA[1][0]; pA0.u[3] = pkA[1][1];
        pA1.u[0] = pkA[2][0]; pA1.u[1] = pkA[2][1]; pA1.u[2] = pkA[3][0]; pA1.u[3] = pkA[3][1];
        pB0.u[0] = pkB[0][0]; pB0.u[1] = pkB[0][1]; pB0.u[2] = pkB[1][0]; pB0.u[3] = pkB[1][1];
        pB1.u[0] = pkB[2][0]; pB1.u[1] = pkB[2][1]; pB1.u[2] = pkB[3][0]; pB1.u[3] = pkB[3][1];
        __builtin_amdgcn_s_setprio(1);
        o = mfma32(v0.b8, pA0.b8, o);
        o = mfma32(v1.b8, pA1.b8, o);
        o = mfma32(v2.b8, pB0.b8, o);
        o = mfma32(v3.b8, pB1.b8, o);
        __builtin_amdgcn_s_setprio(0);
    }

    // ---- store partials (unnormalized O bf16, m/l f32) ----
    const int qt = blockIdx.x * 2 + qh;
    uint4 s0, s1;
    s0.x = cvt_pk(o[0], o[1]);   s0.y = cvt_pk(o[2], o[3]);
    s0.z = cvt_pk(o[4], o[5]);   s0.w = cvt_pk(o[6], o[7]);
    s1.x = cvt_pk(o[8], o[9]);   s1.y = cvt_pk(o[10], o[11]);
    s1.z = cvt_pk(o[12], o[13]); s1.w = cvt_pk(o[14], o[15]);
    size_t base = ((((size_t)hb * 2 + half) * 32 + qt) * 2) * 64 + lane;
    partO[base] = s0;
    partO[base + 64] = s1;
    if (!hi)
        ml[((size_t)hb * 2 + half) * 1024 + q0 + la] = make_float2(mst, lst);
}

// ---------------- K2b: combine kv-halves + fused gate (32x32 MFMA) -> ogb ----------------
// grid 256, block 512 = 8 waves; wave = one (hb, 32q tile).
__global__ __launch_bounds__(512) void attn_combine(
    const uint4* __restrict__ partO, const float2* __restrict__ ml,
    const float* __restrict__ gate_w, const float* __restrict__ gate_b,
    unsigned short* __restrict__ ogb)
{
    const int t = threadIdx.x, lane = t & 63, w = t >> 6;
    const int la = lane & 31, hi = lane >> 5;
    const int widx = blockIdx.x * 8 + w;
    const int hb = widx >> 5, qt = widx & 31;
    const int q0 = qt * 32, h = hb & 7;

    size_t b0 = ((((size_t)hb * 2 + 0) * 32 + qt) * 2) * 64 + lane;
    size_t b1 = ((((size_t)hb * 2 + 1) * 32 + qt) * 2) * 64 + lane;
    uint4 pa0 = partO[b0], pa1 = partO[b0 + 64];
    uint4 pb0 = partO[b1], pb1 = partO[b1 + 64];
    float2 ab0 = ml[((size_t)hb * 2 + 0) * 1024 + q0 + la];
    float2 ab1 = ml[((size_t)hb * 2 + 1) * 1024 + q0 + la];
    float M = fmaxf(ab0.x, ab1.x);
    float w0 = ex2(ab0.x - M), w1 = ex2(ab1.x - M);
    float li = 1.0f / (ab0.y * w0 + ab1.y * w1);
    w0 *= li; w1 *= li;

    unsigned wa[8] = {pa0.x, pa0.y, pa0.z, pa0.w, pa1.x, pa1.y, pa1.z, pa1.w};
    unsigned wc[8] = {pb0.x, pb0.y, pb0.z, pb0.w, pb1.x, pb1.y, pb1.z, pb1.w};
    float o[16];
#pragma unroll
    for (int a = 0; a < 4; ++a) {
        o[4 * a + 0] = bflo(wa[2 * a]) * w0 + bflo(wc[2 * a]) * w1;
        o[4 * a + 1] = bfhi(wa[2 * a]) * w0 + bfhi(wc[2 * a]) * w1;
        o[4 * a + 2] = bflo(wa[2 * a + 1]) * w0 + bflo(wc[2 * a + 1]) * w1;
        o[4 * a + 3] = bfhi(wa[2 * a + 1]) * w0 + bfhi(wc[2 * a + 1]) * w1;
    }

    // gate_w A-frags: gate_w[h][c=la][d = t16*16 + hi*8 + j]
    bf16x8_t ga0, ga1;
    {
        const float* gw = gate_w + (size_t)(h * 32 + la) * 32 + hi * 8;
        V16 m;
        f32x4_t a0 = *(const f32x4_t*)gw, a1 = *(const f32x4_t*)(gw + 4);
        m.u[0] = cvt_pk(a0[0], a0[1]); m.u[1] = cvt_pk(a0[2], a0[3]);
        m.u[2] = cvt_pk(a1[0], a1[1]); m.u[3] = cvt_pk(a1[2], a1[3]);
        ga0 = m.b8;
        f32x4_t a2 = *(const f32x4_t*)(gw + 16), a3 = *(const f32x4_t*)(gw + 20);
        m.u[0] = cvt_pk(a2[0], a2[1]); m.u[1] = cvt_pk(a2[2], a2[3]);
        m.u[2] = cvt_pk(a3[0], a3[1]); m.u[3] = cvt_pk(a3[2], a3[3]);
        ga1 = m.b8;
    }

    // pack O -> bf16, permlane into B-frags, gate GEMM
    unsigned pk[4][2];
#pragma unroll
    for (int a = 0; a < 4; ++a) {
        pk[a][0] = cvt_pk(o[4 * a], o[4 * a + 1]);
        pk[a][1] = cvt_pk(o[4 * a + 2], o[4 * a + 3]);
    }
    pl32swap(pk[0][0], pk[1][0]); pl32swap(pk[0][1], pk[1][1]);
    pl32swap(pk[2][0], pk[3][0]); pl32swap(pk[2][1], pk[3][1]);
    V16 oB0, oB1;
    oB0.u[0] = pk[0][0]; oB0.u[1] = pk[0][1]; oB0.u[2] = pk[1][0]; oB0.u[3] = pk[1][1];
    oB1.u[0] = pk[2][0]; oB1.u[1] = pk[2][1]; oB1.u[2] = pk[3][0]; oB1.u[3] = pk[3][1];
    f32x16_t gacc = {};
    gacc = mfma32(ga0, oB0.b8, gacc);
    gacc = mfma32(ga1, oB1.b8, gacc);

#pragma unroll
    for (int a = 0; a < 4; ++a) {
        f32x4_t gb4 = *(const f32x4_t*)(gate_b + h * 32 + 8 * a + 4 * hi);
#pragma unroll
        for (int i = 0; i < 4; ++i) {
            float garg = gacc[4 * a + i] + gb4[i];
            float sg = 1.0f / (1.0f + ex2(-garg * LOG2E_F));
            o[4 * a + i] *= sg;
        }
    }

    unsigned* ogp = (unsigned*)ogb + ((size_t)(hb * 1024 + q0 + la)) * 16;
#pragma unroll
    for (int a = 0; a < 4; ++a) {
        uint2 st;
        st.x = cvt_pk(o[4 * a], o[4 * a + 1]);
        st.y = cvt_pk(o[4 * a + 2], o[4 * a + 3]);
        *(uint2*)&ogp[4 * a + 2 * hi] = st;
    }
}

// ---------------- K3: out-proj + residual + layernorm via MFMA ----------------
__global__ __launch_bounds__(512) void proj_ln_mfma(
    const unsigned short* __restrict__ ogb, const float* __restrict__ x,
    const unsigned short* __restrict__ wob, const float* __restrict__ bo,
    const float* __restrict__ ln_g, const float* __restrict__ ln_b,
    float* __restrict__ out)
{
    __shared__ float s1l[8][16];
    __shared__ float s2l[8][16];
    const int t = threadIdx.x;
    const int lane = t & 63, w = t >> 6;
    const int r = lane & 15, g = lane >> 4;
    const int m0 = blockIdx.x * 16;
    const int bs = m0 >> 10, l0 = m0 & 1023;
    const int n0 = w * 32;

    const uint4* ap = (const uint4*)ogb;
    const uint4* bp = (const uint4*)wob;

    f32x4_t acc[2] = {};
#pragma unroll
    for (int kt = 0; kt < 8; ++kt) {
        V16 a0, b0, b1;
        a0.u4 = ap[((size_t)(bs * 8 + kt) * 1024 + l0 + r) * 4 + g];
        b0.u4 = bp[(n0 + r) * 32 + kt * 4 + g];
        b1.u4 = bp[(n0 + 16 + r) * 32 + kt * 4 + g];
        acc[0] = mfma16(a0.b8, b0.b8, acc[0]);
        acc[1] = mfma16(a0.b8, b1.b8, acc[1]);
    }

    float bo0 = bo[n0 + r], bo1 = bo[n0 + 16 + r];
#pragma unroll
    for (int e = 0; e < 4; ++e) {
        int m = m0 + g * 4 + e;
        acc[0][e] += bo0 + x[(size_t)m * 256 + n0 + r];
        acc[1][e] += bo1 + x[(size_t)m * 256 + n0 + 16 + r];
    }
#pragma unroll
    for (int e = 0; e < 4; ++e) {
        float sm = acc[0][e] + acc[1][e];
        float sq = acc[0][e] * acc[0][e] + acc[1][e] * acc[1][e];
        sm += __shfl_xor(sm, 1, 64); sq += __shfl_xor(sq, 1, 64);
        sm += __shfl_xor(sm, 2, 64); sq += __shfl_xor(sq, 2, 64);
        sm += __shfl_xor(sm, 4, 64); sq += __shfl_xor(sq, 4, 64);
        sm += __shfl_xor(sm, 8, 64); sq += __shfl_xor(sq, 8, 64);
        if (r == 0) { s1l[w][g * 4 + e] = sm; s2l[w][g * 4 + e] = sq; }
    }
    __syncthreads();

    float g0 = ln_g[n0 + r], g1 = ln_g[n0 + 16 + r];
    float b0 = ln_b[n0 + r], b1 = ln_b[n0 + 16 + r];
#pragma unroll
    for (int e = 0; e < 4; ++e) {
        int mloc = g * 4 + e;
        float sm = 0.f, sq = 0.f;
#pragma unroll
        for (int wv = 0; wv < 8; ++wv) { sm += s1l[wv][mloc]; sq += s2l[wv][mloc]; }
        float mu = sm * (1.0f / 256.0f);
        float var = sq * (1.0f / 256.0f) - mu * mu;
        float rs = rsqrtf(var + 1e-5f);
        int m = m0 + mloc;
        out[(size_t)m * 256 + n0 + r]      = (acc[0][e] - mu) * rs * g0 + b0;
        out[(size_t)m * 256 + n0 + 16 + r] = (acc[1][e] - mu) * rs * g1 + b1;
    }
}

extern "C" void kernel_launch(void* const* d_in, const int* in_sizes, int n_in,
                              void* d_out, int out_size, void* d_ws, size_t ws_size,
                              hipStream_t stream)
{
    (void)in_sizes; (void)n_in; (void)out_size; (void)ws_size;
    const float* x      = (const float*)d_in[0];
    const float* bulk   = (const float*)d_in[1];
    const float* Wq     = (const float*)d_in[2];
    const float* bq     = (const float*)d_in[3];
    const float* Wk     = (const float*)d_in[4];
    const float* bk     = (const float*)d_in[5];
    const float* Wv     = (const float*)d_in[6];
    const float* bv     = (const float*)d_in[7];
    const float* Wo     = (const float*)d_in[8];
    const float* bo     = (const float*)d_in[9];
    const float* conv_w = (const float*)d_in[10];
    const float* conv_b = (const float*)d_in[11];
    const float* gate_w = (const float*)d_in[12];
    const float* gate_b = (const float*)d_in[13];
    const float* ln_g   = (const float*)d_in[14];
    const float* ln_b   = (const float*)d_in[15];
    float* out = (float*)d_out;

    char* ws = (char*)d_ws;
    unsigned short* xb  = (unsigned short*)ws;                    // 4 MB (dead after qkv)
    unsigned short* wb  = (unsigned short*)(ws + (4u << 20));     // 512 KB
    unsigned short* qws = (unsigned short*)(ws + (4u << 20) + (512u << 10)); // 4 MB
    unsigned short* kws = qws + 2097152;                          // 4 MB
    unsigned short* vws = qws + 4194304;                          // 4 MB (dead after transpose_v)
    unsigned short* vT  = qws + 6291456;                          // 4 MB
    uint4*          partO = (uint4*)(ws + (20u << 20) + (512u << 10)); // 8 MB -> total 28.5 MB
    float2*         mlp = (float2*)ws;                            // 1 MB, aliases dead xb
    unsigned short* ogb = vws;                                    // aliases dead vws
    unsigned short* wob = wb + 3 * 65536;

    conv_bf16<<<dim3(2048, 5), 256, 0, stream>>>(x, Wq, Wk, Wv, Wo, xb, wb);
    qkv_mfma<<<dim3(128, 12), 256, 0, stream>>>(xb, wb, bq, bk, bv, qws, kws, vws);
    transpose_v<<<dim3(4, 64), 256, 0, stream>>>(vws, vT);
    attn_mfma<<<dim3(16, 2, 16), 512, 0, stream>>>(qws, kws, vT, bulk, conv_w, conv_b,
                                                   partO, mlp);
    attn_combine<<<256, 512, 0, stream>>>(partO, mlp, gate_w, gate_b, ogb);
    proj_ln_mfma<<<512, 512, 0, stream>>>(ogb, x, wob, bo, ln_g, ln_b, out);
}